// Round 1
// baseline (466.237 us; speedup 1.0000x reference)
//
#include <hip/hip_runtime.h>

typedef __attribute__((ext_vector_type(8))) short bf16x8;
typedef __attribute__((ext_vector_type(8))) unsigned short ushort8;
typedef __attribute__((ext_vector_type(4))) float f32x4;
typedef unsigned short u16;

__device__ inline float bf2f(u16 u) {
    unsigned int x = ((unsigned int)u) << 16;
    float f; __builtin_memcpy(&f, &x, 4); return f;
}
__device__ inline u16 f2bf(float f) {
    unsigned int x; __builtin_memcpy(&x, &f, 4);
    unsigned int r = (x + 0x7FFFu + ((x >> 16) & 1u)) >> 16;
    return (u16)r;
}
__device__ inline void store_out(u16* p, float v) { *p = f2bf(v); }
__device__ inline void store_out(float* p, float v) { *p = v; }

// ---------------- prep kernels ----------------
__global__ __launch_bounds__(256) void f32_to_bf16_kernel(const float* __restrict__ src,
                                                          u16* __restrict__ dst, int n8) {
    int i = blockIdx.x * 256 + threadIdx.x;
    if (i >= n8) return;
    float4 a = *(const float4*)(src + (size_t)i * 8);
    float4 b = *(const float4*)(src + (size_t)i * 8 + 4);
    ushort8 o;
    o[0] = f2bf(a.x); o[1] = f2bf(a.y); o[2] = f2bf(a.z); o[3] = f2bf(a.w);
    o[4] = f2bf(b.x); o[5] = f2bf(b.y); o[6] = f2bf(b.z); o[7] = f2bf(b.w);
    *(ushort8*)(dst + (size_t)i * 8) = o;
}

// rope table: [2048][64][2] f32 from freqs [1024][64][2]
__global__ __launch_bounds__(256) void build_rope_kernel(const float* __restrict__ freqs,
                                                         float* __restrict__ rope) {
    int i = blockIdx.x * 256 + threadIdx.x;  // 0..131071
    int s = i >> 6, j = i & 63;
    int fi = s >> 8, hi = (s >> 4) & 15, wi = s & 15;
    int pos = (j < 22) ? fi : ((j < 43) ? hi : wi);
    rope[s * 128 + j * 2]     = freqs[pos * 128 + j * 2];
    rope[s * 128 + j * 2 + 1] = freqs[pos * 128 + j * 2 + 1];
}

// ---------------- GEMM: A[M,K] bf16 row-major, B[N,K] bf16 row-major (B^T gemm), + bias ----------------
template <typename OutT>
__global__ __launch_bounds__(256) void gemm_bt(const u16* __restrict__ A, const u16* __restrict__ Bw,
                                               const float* __restrict__ bias, OutT* __restrict__ C,
                                               int M, int N, int K) {
    __shared__ __align__(16) u16 As[128 * 32];
    __shared__ __align__(16) u16 Bs[128 * 32];
    const int tid = threadIdx.x;
    const int w = tid >> 6, l = tid & 63;
    const int lg = l >> 4, li = l & 15;
    const int row0 = blockIdx.x * 128, col0 = blockIdx.y * 128;
    const int wr = (w >> 1) * 64, wc = (w & 1) * 64;

    f32x4 acc[4][4] = {};

    for (int k0 = 0; k0 < K; k0 += 32) {
#pragma unroll
        for (int c = 0; c < 2; ++c) {
            int idx = c * 256 + tid;           // 0..511 chunks of 8 elems
            int r = idx >> 2, col8 = (idx & 3) * 8;
            const u16* ga = A + (size_t)(row0 + r) * K + k0 + col8;
            const u16* gb = Bw + (size_t)(col0 + r) * K + k0 + col8;
            __builtin_amdgcn_global_load_lds((const __attribute__((address_space(1))) void*)ga,
                (__attribute__((address_space(3))) void*)((char*)As + c * 4096 + w * 1024), 16, 0, 0);
            __builtin_amdgcn_global_load_lds((const __attribute__((address_space(1))) void*)gb,
                (__attribute__((address_space(3))) void*)((char*)Bs + c * 4096 + w * 1024), 16, 0, 0);
        }
        __syncthreads();
        bf16x8 af[4], bfr[4];
#pragma unroll
        for (int m = 0; m < 4; ++m) af[m] = *(const bf16x8*)(As + (wr + m * 16 + li) * 32 + lg * 8);
#pragma unroll
        for (int n = 0; n < 4; ++n) bfr[n] = *(const bf16x8*)(Bs + (wc + n * 16 + li) * 32 + lg * 8);
#pragma unroll
        for (int m = 0; m < 4; ++m)
#pragma unroll
            for (int n = 0; n < 4; ++n)
                acc[m][n] = __builtin_amdgcn_mfma_f32_16x16x32_bf16(af[m], bfr[n], acc[m][n], 0, 0, 0);
        __syncthreads();
    }

#pragma unroll
    for (int m = 0; m < 4; ++m) {
#pragma unroll
        for (int n = 0; n < 4; ++n) {
#pragma unroll
            for (int j = 0; j < 4; ++j) {
                int r = row0 + wr + m * 16 + lg * 4 + j;
                int cc = col0 + wc + n * 16 + li;
                float v = acc[m][n][j] + bias[cc];
                store_out(&C[(size_t)r * N + cc], v);
            }
        }
    }
}

// ---------------- rmsnorm + rope + head-major scatter ----------------
// qkv: [4096][4608] bf16 (q | k | v).  outputs: [B=2][H=12][S=2048][D=128] bf16
__global__ __launch_bounds__(256) void rmsrope_kernel(const u16* __restrict__ qkv,
                                                      const float* __restrict__ wq_n,
                                                      const float* __restrict__ wk_n,
                                                      const float* __restrict__ rope,
                                                      u16* __restrict__ qh, u16* __restrict__ kh,
                                                      u16* __restrict__ vh) {
    int row = blockIdx.x;              // 0..4095
    int b = row >> 11, s = row & 2047;
    int t = threadIdx.x;
    const u16* pr = qkv + (size_t)row * 4608;
    int c0 = t * 6;

    float q[6], k[6];
    u16 vb[6];
#pragma unroll
    for (int i = 0; i < 3; ++i) {
        ushort2 uq = *(const ushort2*)(pr + c0 + 2 * i);
        ushort2 uk = *(const ushort2*)(pr + 1536 + c0 + 2 * i);
        ushort2 uv = *(const ushort2*)(pr + 3072 + c0 + 2 * i);
        q[2 * i] = bf2f(uq.x); q[2 * i + 1] = bf2f(uq.y);
        k[2 * i] = bf2f(uk.x); k[2 * i + 1] = bf2f(uk.y);
        vb[2 * i] = uv.x; vb[2 * i + 1] = uv.y;
    }
    float sq = 0.f, sk = 0.f;
#pragma unroll
    for (int i = 0; i < 6; ++i) { sq += q[i] * q[i]; sk += k[i] * k[i]; }
#pragma unroll
    for (int off = 32; off >= 1; off >>= 1) {
        sq += __shfl_down(sq, off);
        sk += __shfl_down(sk, off);
    }
    __shared__ float red[8];
    int w = t >> 6, l = t & 63;
    if (l == 0) { red[w] = sq; red[w + 4] = sk; }
    __syncthreads();
    float rq = rsqrtf((red[0] + red[1] + red[2] + red[3]) * (1.0f / 1536.0f) + 1e-6f);
    float rk = rsqrtf((red[4] + red[5] + red[6] + red[7]) * (1.0f / 1536.0f) + 1e-6f);

#pragma unroll
    for (int i = 0; i < 3; ++i) {
        int c = c0 + 2 * i;
        int h = c >> 7, d = c & 127;
        float cs = rope[s * 128 + d];
        float sn = rope[s * 128 + d + 1];
        float qa = q[2 * i] * rq * wq_n[c], qb = q[2 * i + 1] * rq * wq_n[c + 1];
        float ka = k[2 * i] * rk * wk_n[c], kb = k[2 * i + 1] * rk * wk_n[c + 1];
        size_t o = ((size_t)(b * 12 + h) * 2048 + s) * 128 + d;
        ushort2 qo, ko, vo;
        qo.x = f2bf(qa * cs - qb * sn); qo.y = f2bf(qa * sn + qb * cs);
        ko.x = f2bf(ka * cs - kb * sn); ko.y = f2bf(ka * sn + kb * cs);
        vo.x = vb[2 * i]; vo.y = vb[2 * i + 1];
        *(ushort2*)(qh + o) = qo;
        *(ushort2*)(kh + o) = ko;
        *(ushort2*)(vh + o) = vo;
    }
}

// ---------------- flash attention ----------------
// q/k/v: [BH=24][2048][128] bf16 head-major. out: [4096][1536] bf16 (b,s major)
__global__ __launch_bounds__(256) void attn_kernel(const u16* __restrict__ qh, const u16* __restrict__ kh,
                                                   const u16* __restrict__ vh, const int* __restrict__ seq_lens,
                                                   u16* __restrict__ aout) {
    const int qt = blockIdx.x;        // 32 q tiles of 64
    const int bh = blockIdx.y;        // 24
    const int b = bh / 12, h = bh % 12;
    const int tid = threadIdx.x;
    const int w = tid >> 6, l = tid & 63;
    const int lg = l >> 4, li = l & 15;
    const int seqlen = seq_lens[b];

    __shared__ __align__(16) u16 Ks[64][136];
    __shared__ __align__(16) u16 Vt[128][72];
    __shared__ __align__(16) u16 Pw[4][16][72];

    const size_t hbase = (size_t)bh * 2048 * 128;
    const u16* kb = kh + hbase;
    const u16* vb = vh + hbase;

    bf16x8 qf[4];
    {
        const u16* qp = qh + hbase + (size_t)(qt * 64 + w * 16 + li) * 128;
#pragma unroll
        for (int kk = 0; kk < 4; ++kk) qf[kk] = *(const bf16x8*)(qp + kk * 32 + lg * 8);
    }

    f32x4 acc[8] = {};
    float m_run[4], l_run[4];
#pragma unroll
    for (int j = 0; j < 4; ++j) { m_run[j] = -3e38f; l_run[j] = 0.f; }

    for (int kv0 = 0; kv0 < 2048; kv0 += 64) {
        __syncthreads();
#pragma unroll
        for (int c = 0; c < 4; ++c) {
            int chunk = c * 256 + tid;          // 0..1023
            int r = chunk >> 4;                 // kv row 0..63
            int col8 = (chunk & 15) * 8;        // d 0..120
            ushort8 k8 = *(const ushort8*)(kb + (size_t)(kv0 + r) * 128 + col8);
            *(ushort8*)(&Ks[r][col8]) = k8;
            ushort8 v8 = *(const ushort8*)(vb + (size_t)(kv0 + r) * 128 + col8);
#pragma unroll
            for (int i = 0; i < 8; ++i) Vt[col8 + i][r] = v8[i];
        }
        __syncthreads();

        // QK^T -> sc[n0][j], row = lg*4+j, col = n0*16+li
        float sc[4][4];
#pragma unroll
        for (int n0 = 0; n0 < 4; ++n0) {
            f32x4 cacc = {0.f, 0.f, 0.f, 0.f};
#pragma unroll
            for (int kk = 0; kk < 4; ++kk) {
                bf16x8 kf = *(const bf16x8*)(&Ks[n0 * 16 + li][kk * 32 + lg * 8]);
                cacc = __builtin_amdgcn_mfma_f32_16x16x32_bf16(qf[kk], kf, cacc, 0, 0, 0);
            }
#pragma unroll
            for (int j = 0; j < 4; ++j) sc[n0][j] = cacc[j] * 0.08838834764831845f;
        }
        if (kv0 + 64 > seqlen) {
#pragma unroll
            for (int n0 = 0; n0 < 4; ++n0)
                if (kv0 + n0 * 16 + li >= seqlen) {
#pragma unroll
                    for (int j = 0; j < 4; ++j) sc[n0][j] = -1e30f;
                }
        }
        // online softmax
#pragma unroll
        for (int j = 0; j < 4; ++j) {
            float v = fmaxf(fmaxf(sc[0][j], sc[1][j]), fmaxf(sc[2][j], sc[3][j]));
#pragma unroll
            for (int off = 8; off >= 1; off >>= 1) v = fmaxf(v, __shfl_xor(v, off));
            float mnew = fmaxf(m_run[j], v);
            float alpha = __expf(m_run[j] - mnew);
            m_run[j] = mnew;
            float ps = 0.f;
#pragma unroll
            for (int n0 = 0; n0 < 4; ++n0) {
                float p = __expf(sc[n0][j] - mnew);
                sc[n0][j] = p;
                ps += p;
            }
#pragma unroll
            for (int off = 8; off >= 1; off >>= 1) ps += __shfl_xor(ps, off);
            l_run[j] = l_run[j] * alpha + ps;
#pragma unroll
            for (int d0 = 0; d0 < 8; ++d0) acc[d0][j] *= alpha;
        }
        // P -> LDS (per wave)
#pragma unroll
        for (int n0 = 0; n0 < 4; ++n0)
#pragma unroll
            for (int j = 0; j < 4; ++j)
                Pw[w][lg * 4 + j][n0 * 16 + li] = f2bf(sc[n0][j]);
        // PV
#pragma unroll
        for (int kk = 0; kk < 2; ++kk) {
            bf16x8 pf = *(const bf16x8*)(&Pw[w][li][kk * 32 + lg * 8]);
#pragma unroll
            for (int d0 = 0; d0 < 8; ++d0) {
                bf16x8 vf = *(const bf16x8*)(&Vt[d0 * 16 + li][kk * 32 + lg * 8]);
                acc[d0] = __builtin_amdgcn_mfma_f32_16x16x32_bf16(pf, vf, acc[d0], 0, 0, 0);
            }
        }
    }

#pragma unroll
    for (int d0 = 0; d0 < 8; ++d0) {
#pragma unroll
        for (int j = 0; j < 4; ++j) {
            float o = acc[d0][j] / l_run[j];
            int qr = qt * 64 + w * 16 + lg * 4 + j;
            size_t off = ((size_t)(b * 2048 + qr)) * 1536 + h * 128 + d0 * 16 + li;
            aout[off] = f2bf(o);
        }
    }
}

// ---------------- host ----------------
extern "C" void kernel_launch(void* const* d_in, const int* in_sizes, int n_in,
                              void* d_out, int out_size, void* d_ws, size_t ws_size,
                              hipStream_t stream) {
    const float* x    = (const float*)d_in[0];
    const int* seqlen = (const int*)d_in[1];
    const float* freqs = (const float*)d_in[3];
    const float* Wq = (const float*)d_in[4];  const float* bq = (const float*)d_in[5];
    const float* Wk = (const float*)d_in[6];  const float* bk = (const float*)d_in[7];
    const float* Wv = (const float*)d_in[8];  const float* bv = (const float*)d_in[9];
    const float* Wo = (const float*)d_in[10]; const float* bo = (const float*)d_in[11];
    const float* wqn = (const float*)d_in[12];
    const float* wkn = (const float*)d_in[13];
    float* out = (float*)d_out;

    char* ws = (char*)d_ws;
    u16*   xb   = (u16*)(ws);                    // 4096*1536*2      = 12,582,912
    u16*   wqkv = (u16*)(ws + 12582912);         // 4608*1536*2      = 14,155,776
    u16*   wob  = (u16*)(ws + 26738688);         // 1536*1536*2      =  4,718,592
    float* bqkv = (float*)(ws + 31457280);       // 4608*4           =     18,432
    float* rope = (float*)(ws + 31475712);       // 2048*128*4       =  1,048,576
    u16*   qkv  = (u16*)(ws + 32524288);         // 4096*4608*2      = 37,748,736
    u16*   qhb  = (u16*)(ws + 70273024);         // 12,582,912
    u16*   khb  = (u16*)(ws + 82855936);         // 12,582,912
    u16*   vhb  = (u16*)(ws + 95438848);         // 12,582,912
    u16*   aob  = (u16*)(ws + 108021760);        // 12,582,912  (end 120,604,672)

    // converts
    f32_to_bf16_kernel<<<3072, 256, 0, stream>>>(x, xb, 786432);
    f32_to_bf16_kernel<<<1152, 256, 0, stream>>>(Wq, wqkv, 294912);
    f32_to_bf16_kernel<<<1152, 256, 0, stream>>>(Wk, wqkv + 2359296, 294912);
    f32_to_bf16_kernel<<<1152, 256, 0, stream>>>(Wv, wqkv + 4718592, 294912);
    f32_to_bf16_kernel<<<1152, 256, 0, stream>>>(Wo, wob, 294912);
    hipMemcpyAsync(bqkv,        bq, 1536 * 4, hipMemcpyDeviceToDevice, stream);
    hipMemcpyAsync(bqkv + 1536, bk, 1536 * 4, hipMemcpyDeviceToDevice, stream);
    hipMemcpyAsync(bqkv + 3072, bv, 1536 * 4, hipMemcpyDeviceToDevice, stream);
    build_rope_kernel<<<512, 256, 0, stream>>>(freqs, rope);

    // QKV projection
    gemm_bt<u16><<<dim3(32, 36), 256, 0, stream>>>(xb, wqkv, bqkv, qkv, 4096, 4608, 1536);
    // rmsnorm + rope + scatter
    rmsrope_kernel<<<4096, 256, 0, stream>>>(qkv, wqn, wkn, rope, qhb, khb, vhb);
    // attention
    attn_kernel<<<dim3(32, 24), 256, 0, stream>>>(qhb, khb, vhb, seqlen, aob);
    // output projection
    gemm_bt<float><<<dim3(32, 12), 256, 0, stream>>>(aob, wob, bo, out, 4096, 1536, 1536);
}

// Round 2
// 285.435 us; speedup vs baseline: 1.6334x; 1.6334x over previous
//
#include <hip/hip_runtime.h>

typedef __attribute__((ext_vector_type(8))) short bf16x8;
typedef __attribute__((ext_vector_type(8))) unsigned short ushort8;
typedef __attribute__((ext_vector_type(4))) float f32x4;
typedef unsigned short u16;

__device__ inline float bf2f(u16 u) {
    unsigned int x = ((unsigned int)u) << 16;
    float f; __builtin_memcpy(&f, &x, 4); return f;
}
__device__ inline u16 f2bf(float f) {
    unsigned int x; __builtin_memcpy(&x, &f, 4);
    unsigned int r = (x + 0x7FFFu + ((x >> 16) & 1u)) >> 16;
    return (u16)r;
}
__device__ inline void store_out(u16* p, float v) { *p = f2bf(v); }
__device__ inline void store_out(float* p, float v) { *p = v; }

// ---------------- prep kernels ----------------
__global__ __launch_bounds__(256) void f32_to_bf16_kernel(const float* __restrict__ src,
                                                          u16* __restrict__ dst, int n8) {
    int i = blockIdx.x * 256 + threadIdx.x;
    if (i >= n8) return;
    float4 a = *(const float4*)(src + (size_t)i * 8);
    float4 b = *(const float4*)(src + (size_t)i * 8 + 4);
    ushort8 o;
    o[0] = f2bf(a.x); o[1] = f2bf(a.y); o[2] = f2bf(a.z); o[3] = f2bf(a.w);
    o[4] = f2bf(b.x); o[5] = f2bf(b.y); o[6] = f2bf(b.z); o[7] = f2bf(b.w);
    *(ushort8*)(dst + (size_t)i * 8) = o;
}

// rope table: [2048][64][2] f32 from freqs [1024][64][2]
__global__ __launch_bounds__(256) void build_rope_kernel(const float* __restrict__ freqs,
                                                         float* __restrict__ rope) {
    int i = blockIdx.x * 256 + threadIdx.x;  // 0..131071
    int s = i >> 6, j = i & 63;
    int fi = s >> 8, hi = (s >> 4) & 15, wi = s & 15;
    int pos = (j < 22) ? fi : ((j < 43) ? hi : wi);
    rope[s * 128 + j * 2]     = freqs[pos * 128 + j * 2];
    rope[s * 128 + j * 2 + 1] = freqs[pos * 128 + j * 2 + 1];
}

// ---------------- GEMM: A[M,K] bf16 row-major, B[N,K] bf16 row-major (B^T gemm), + bias ----------------
template <typename OutT>
__global__ __launch_bounds__(256) void gemm_bt(const u16* __restrict__ A, const u16* __restrict__ Bw,
                                               const float* __restrict__ bias, OutT* __restrict__ C,
                                               int M, int N, int K) {
    __shared__ __align__(16) u16 As[128 * 32];
    __shared__ __align__(16) u16 Bs[128 * 32];
    const int tid = threadIdx.x;
    const int w = tid >> 6, l = tid & 63;
    const int lg = l >> 4, li = l & 15;
    const int row0 = blockIdx.x * 128, col0 = blockIdx.y * 128;
    const int wr = (w >> 1) * 64, wc = (w & 1) * 64;

    f32x4 acc[4][4] = {};

    for (int k0 = 0; k0 < K; k0 += 32) {
#pragma unroll
        for (int c = 0; c < 2; ++c) {
            int idx = c * 256 + tid;           // 0..511 chunks of 8 elems
            int r = idx >> 2, col8 = (idx & 3) * 8;
            const u16* ga = A + (size_t)(row0 + r) * K + k0 + col8;
            const u16* gb = Bw + (size_t)(col0 + r) * K + k0 + col8;
            __builtin_amdgcn_global_load_lds((const __attribute__((address_space(1))) void*)ga,
                (__attribute__((address_space(3))) void*)((char*)As + c * 4096 + w * 1024), 16, 0, 0);
            __builtin_amdgcn_global_load_lds((const __attribute__((address_space(1))) void*)gb,
                (__attribute__((address_space(3))) void*)((char*)Bs + c * 4096 + w * 1024), 16, 0, 0);
        }
        __syncthreads();
        bf16x8 af[4], bfr[4];
#pragma unroll
        for (int m = 0; m < 4; ++m) af[m] = *(const bf16x8*)(As + (wr + m * 16 + li) * 32 + lg * 8);
#pragma unroll
        for (int n = 0; n < 4; ++n) bfr[n] = *(const bf16x8*)(Bs + (wc + n * 16 + li) * 32 + lg * 8);
#pragma unroll
        for (int m = 0; m < 4; ++m)
#pragma unroll
            for (int n = 0; n < 4; ++n)
                acc[m][n] = __builtin_amdgcn_mfma_f32_16x16x32_bf16(af[m], bfr[n], acc[m][n], 0, 0, 0);
        __syncthreads();
    }

#pragma unroll
    for (int m = 0; m < 4; ++m) {
#pragma unroll
        for (int n = 0; n < 4; ++n) {
#pragma unroll
            for (int j = 0; j < 4; ++j) {
                int r = row0 + wr + m * 16 + lg * 4 + j;
                int cc = col0 + wc + n * 16 + li;
                float v = acc[m][n][j] + bias[cc];
                store_out(&C[(size_t)r * N + cc], v);
            }
        }
    }
}

// ---------------- rmsnorm + rope + head-major scatter (q,k only) ----------------
// qkv: [4096][4608] bf16 (q | k | v).  outputs: [B=2][H=12][S=2048][D=128] bf16
__global__ __launch_bounds__(256) void rmsrope_kernel(const u16* __restrict__ qkv,
                                                      const float* __restrict__ wq_n,
                                                      const float* __restrict__ wk_n,
                                                      const float* __restrict__ rope,
                                                      u16* __restrict__ qh, u16* __restrict__ kh) {
    int row = blockIdx.x;              // 0..4095
    int b = row >> 11, s = row & 2047;
    int t = threadIdx.x;
    const u16* pr = qkv + (size_t)row * 4608;
    int c0 = t * 6;

    float q[6], k[6];
#pragma unroll
    for (int i = 0; i < 3; ++i) {
        ushort2 uq = *(const ushort2*)(pr + c0 + 2 * i);
        ushort2 uk = *(const ushort2*)(pr + 1536 + c0 + 2 * i);
        q[2 * i] = bf2f(uq.x); q[2 * i + 1] = bf2f(uq.y);
        k[2 * i] = bf2f(uk.x); k[2 * i + 1] = bf2f(uk.y);
    }
    float sq = 0.f, sk = 0.f;
#pragma unroll
    for (int i = 0; i < 6; ++i) { sq += q[i] * q[i]; sk += k[i] * k[i]; }
#pragma unroll
    for (int off = 32; off >= 1; off >>= 1) {
        sq += __shfl_down(sq, off);
        sk += __shfl_down(sk, off);
    }
    __shared__ float red[8];
    int w = t >> 6, l = t & 63;
    if (l == 0) { red[w] = sq; red[w + 4] = sk; }
    __syncthreads();
    float rq = rsqrtf((red[0] + red[1] + red[2] + red[3]) * (1.0f / 1536.0f) + 1e-6f);
    float rk = rsqrtf((red[4] + red[5] + red[6] + red[7]) * (1.0f / 1536.0f) + 1e-6f);

#pragma unroll
    for (int i = 0; i < 3; ++i) {
        int c = c0 + 2 * i;
        int h = c >> 7, d = c & 127;
        float cs = rope[s * 128 + d];
        float sn = rope[s * 128 + d + 1];
        float qa = q[2 * i] * rq * wq_n[c], qb = q[2 * i + 1] * rq * wq_n[c + 1];
        float ka = k[2 * i] * rk * wk_n[c], kb = k[2 * i + 1] * rk * wk_n[c + 1];
        size_t o = ((size_t)(b * 12 + h) * 2048 + s) * 128 + d;
        ushort2 qo, ko;
        qo.x = f2bf(qa * cs - qb * sn); qo.y = f2bf(qa * sn + qb * cs);
        ko.x = f2bf(ka * cs - kb * sn); ko.y = f2bf(ka * sn + kb * cs);
        *(ushort2*)(qh + o) = qo;
        *(ushort2*)(kh + o) = ko;
    }
}

// ---------------- V transpose: qkv v-slice [4096][4608] -> vT [24][128][2048] ----------------
// grid: (s_tile=32, d_tile=2, bh=24), 256 threads
__global__ __launch_bounds__(256) void vtrans_kernel(const u16* __restrict__ qkv,
                                                     u16* __restrict__ vt) {
    const int s0 = blockIdx.x * 64;
    const int d0 = blockIdx.y * 64;
    const int bh = blockIdx.z;
    const int b = bh / 12, h = bh % 12;
    const int t = threadIdx.x;

    __shared__ __align__(16) u16 L[64 * 72];   // rows s (0..63), swizzled d-blocks

    // load 64x64 tile: v[b][s0+s][h*128 + d0 + d]
#pragma unroll
    for (int j = 0; j < 2; ++j) {
        int idx = j * 256 + t;                  // 0..511
        int s = idx >> 3, c8 = idx & 7;
        ushort8 v8 = *(const ushort8*)(qkv + (size_t)(b * 2048 + s0 + s) * 4608 + 3072 + h * 128 + d0 + c8 * 8);
        int pb = c8 ^ ((s >> 3) & 7);
        *(ushort8*)(L + s * 72 + pb * 8) = v8;
    }
    __syncthreads();
    // store transposed: vt[bh][d0+d][s0 + s8*8 .. +8]
#pragma unroll
    for (int j = 0; j < 2; ++j) {
        int idx = j * 256 + t;
        int d = idx >> 3, s8 = idx & 7;
        ushort8 o;
#pragma unroll
        for (int i = 0; i < 8; ++i) {
            o[i] = L[(s8 * 8 + i) * 72 + (((d >> 3) ^ s8) << 3) + (d & 7)];
        }
        *(ushort8*)(vt + (size_t)bh * 128 * 2048 + (size_t)(d0 + d) * 2048 + s0 + s8 * 8) = o;
    }
}

// ---------------- flash attention ----------------
// qh/kh: [BH=24][2048][128] bf16; vt: [24][128][2048] bf16 (V^T). out: [4096][1536] bf16
__global__ __launch_bounds__(256) void attn_kernel(const u16* __restrict__ qh, const u16* __restrict__ kh,
                                                   const u16* __restrict__ vt, const int* __restrict__ seq_lens,
                                                   u16* __restrict__ aout) {
    const int qt = blockIdx.x;        // 32 q tiles of 64
    const int bh = blockIdx.y;        // 24
    const int b = bh / 12, h = bh % 12;
    const int tid = threadIdx.x;
    const int w = tid >> 6, l = tid & 63;
    const int lg = l >> 4, li = l & 15;
    const int seqlen = seq_lens[b];

    __shared__ __align__(16) u16 Ks[64 * 128];   // [kv][d], block-swizzled
    __shared__ __align__(16) u16 Vs[128 * 64];   // [d][kv], block-swizzled
    __shared__ __align__(16) u16 Pw[4][16 * 72];

    const size_t hbase = (size_t)bh * 2048 * 128;
    const u16* kb = kh + hbase;
    const u16* vtb = vt + hbase;      // [128][2048]

    bf16x8 qf[4];
    {
        const u16* qp = qh + hbase + (size_t)(qt * 64 + w * 16 + li) * 128;
#pragma unroll
        for (int kk = 0; kk < 4; ++kk) qf[kk] = *(const bf16x8*)(qp + kk * 32 + lg * 8);
    }

    f32x4 acc[8] = {};
    float m_run[4], l_run[4];
#pragma unroll
    for (int j = 0; j < 4; ++j) { m_run[j] = -3e38f; l_run[j] = 0.f; }

    for (int kv0 = 0; kv0 < 2048; kv0 += 64) {
        __syncthreads();
#pragma unroll
        for (int i = 0; i < 4; ++i) {
            int p = i * 256 + tid;             // 16B block index 0..1023
            // K tile: 64 rows x 16 blocks, phys block pc holds logical (pc ^ (row&15))
            int kr = p >> 4, kc = p & 15;
            __builtin_amdgcn_global_load_lds(
                (const __attribute__((address_space(1))) void*)(kb + (size_t)(kv0 + kr) * 128 + ((kc ^ (kr & 15)) << 3)),
                (__attribute__((address_space(3))) void*)((char*)Ks + (i * 256 + w * 64) * 16), 16, 0, 0);
            // V^T tile: 128 rows x 8 blocks, phys block pc holds logical (pc ^ (row&7))
            int vr = p >> 3, vc = p & 7;
            __builtin_amdgcn_global_load_lds(
                (const __attribute__((address_space(1))) void*)(vtb + (size_t)vr * 2048 + kv0 + ((vc ^ (vr & 7)) << 3)),
                (__attribute__((address_space(3))) void*)((char*)Vs + (i * 256 + w * 64) * 16), 16, 0, 0);
        }
        __syncthreads();

        // QK^T -> sc[n0][j], row = lg*4+j, col = n0*16+li
        float sc[4][4];
#pragma unroll
        for (int n0 = 0; n0 < 4; ++n0) {
            f32x4 cacc = {0.f, 0.f, 0.f, 0.f};
#pragma unroll
            for (int kk = 0; kk < 4; ++kk) {
                bf16x8 kf = *(const bf16x8*)(Ks + (n0 * 16 + li) * 128 + (((kk * 4 + lg) ^ li) << 3));
                cacc = __builtin_amdgcn_mfma_f32_16x16x32_bf16(qf[kk], kf, cacc, 0, 0, 0);
            }
#pragma unroll
            for (int j = 0; j < 4; ++j) sc[n0][j] = cacc[j] * 0.08838834764831845f;
        }
        if (kv0 + 64 > seqlen) {
#pragma unroll
            for (int n0 = 0; n0 < 4; ++n0)
                if (kv0 + n0 * 16 + li >= seqlen) {
#pragma unroll
                    for (int j = 0; j < 4; ++j) sc[n0][j] = -1e30f;
                }
        }
        // online softmax
#pragma unroll
        for (int j = 0; j < 4; ++j) {
            float v = fmaxf(fmaxf(sc[0][j], sc[1][j]), fmaxf(sc[2][j], sc[3][j]));
#pragma unroll
            for (int off = 8; off >= 1; off >>= 1) v = fmaxf(v, __shfl_xor(v, off));
            float mnew = fmaxf(m_run[j], v);
            float alpha = __expf(m_run[j] - mnew);
            m_run[j] = mnew;
            float ps = 0.f;
#pragma unroll
            for (int n0 = 0; n0 < 4; ++n0) {
                float p = __expf(sc[n0][j] - mnew);
                sc[n0][j] = p;
                ps += p;
            }
#pragma unroll
            for (int off = 8; off >= 1; off >>= 1) ps += __shfl_xor(ps, off);
            l_run[j] = l_run[j] * alpha + ps;
#pragma unroll
            for (int d0 = 0; d0 < 8; ++d0) acc[d0][j] *= alpha;
        }
        // P -> LDS (per wave)
#pragma unroll
        for (int n0 = 0; n0 < 4; ++n0)
#pragma unroll
            for (int j = 0; j < 4; ++j)
                Pw[w][(lg * 4 + j) * 72 + n0 * 16 + li] = f2bf(sc[n0][j]);
        // PV
#pragma unroll
        for (int kk = 0; kk < 2; ++kk) {
            bf16x8 pf = *(const bf16x8*)(Pw[w] + li * 72 + kk * 32 + lg * 8);
#pragma unroll
            for (int d0 = 0; d0 < 8; ++d0) {
                bf16x8 vf = *(const bf16x8*)(Vs + (d0 * 16 + li) * 64 + (((kk * 4 + lg) ^ (li & 7)) << 3));
                acc[d0] = __builtin_amdgcn_mfma_f32_16x16x32_bf16(pf, vf, acc[d0], 0, 0, 0);
            }
        }
    }

#pragma unroll
    for (int d0 = 0; d0 < 8; ++d0) {
#pragma unroll
        for (int j = 0; j < 4; ++j) {
            float o = acc[d0][j] / l_run[j];
            int qr = qt * 64 + w * 16 + lg * 4 + j;
            size_t off = ((size_t)(b * 2048 + qr)) * 1536 + h * 128 + d0 * 16 + li;
            aout[off] = f2bf(o);
        }
    }
}

// ---------------- host ----------------
extern "C" void kernel_launch(void* const* d_in, const int* in_sizes, int n_in,
                              void* d_out, int out_size, void* d_ws, size_t ws_size,
                              hipStream_t stream) {
    const float* x    = (const float*)d_in[0];
    const int* seqlen = (const int*)d_in[1];
    const float* freqs = (const float*)d_in[3];
    const float* Wq = (const float*)d_in[4];  const float* bq = (const float*)d_in[5];
    const float* Wk = (const float*)d_in[6];  const float* bk = (const float*)d_in[7];
    const float* Wv = (const float*)d_in[8];  const float* bv = (const float*)d_in[9];
    const float* Wo = (const float*)d_in[10]; const float* bo = (const float*)d_in[11];
    const float* wqn = (const float*)d_in[12];
    const float* wkn = (const float*)d_in[13];
    float* out = (float*)d_out;

    char* ws = (char*)d_ws;
    u16*   xb   = (u16*)(ws);                    // 4096*1536*2      = 12,582,912
    u16*   wqkv = (u16*)(ws + 12582912);         // 4608*1536*2      = 14,155,776
    u16*   wob  = (u16*)(ws + 26738688);         // 1536*1536*2      =  4,718,592
    float* bqkv = (float*)(ws + 31457280);       // 4608*4           =     18,432
    float* rope = (float*)(ws + 31475712);       // 2048*128*4       =  1,048,576
    u16*   qkv  = (u16*)(ws + 32524288);         // 4096*4608*2      = 37,748,736
    u16*   qhb  = (u16*)(ws + 70273024);         // 12,582,912
    u16*   khb  = (u16*)(ws + 82855936);         // 12,582,912
    u16*   vtb  = (u16*)(ws + 95438848);         // 12,582,912 (V^T [24][128][2048])
    u16*   aob  = (u16*)(ws + 108021760);        // 12,582,912  (end 120,604,672)

    // converts
    f32_to_bf16_kernel<<<3072, 256, 0, stream>>>(x, xb, 786432);
    f32_to_bf16_kernel<<<1152, 256, 0, stream>>>(Wq, wqkv, 294912);
    f32_to_bf16_kernel<<<1152, 256, 0, stream>>>(Wk, wqkv + 2359296, 294912);
    f32_to_bf16_kernel<<<1152, 256, 0, stream>>>(Wv, wqkv + 4718592, 294912);
    f32_to_bf16_kernel<<<1152, 256, 0, stream>>>(Wo, wob, 294912);
    hipMemcpyAsync(bqkv,        bq, 1536 * 4, hipMemcpyDeviceToDevice, stream);
    hipMemcpyAsync(bqkv + 1536, bk, 1536 * 4, hipMemcpyDeviceToDevice, stream);
    hipMemcpyAsync(bqkv + 3072, bv, 1536 * 4, hipMemcpyDeviceToDevice, stream);
    build_rope_kernel<<<512, 256, 0, stream>>>(freqs, rope);

    // QKV projection
    gemm_bt<u16><<<dim3(32, 36), 256, 0, stream>>>(xb, wqkv, bqkv, qkv, 4096, 4608, 1536);
    // rmsnorm + rope + scatter (q,k) ; V transpose
    rmsrope_kernel<<<4096, 256, 0, stream>>>(qkv, wqn, wkn, rope, qhb, khb);
    vtrans_kernel<<<dim3(32, 2, 24), 256, 0, stream>>>(qkv, vtb);
    // attention
    attn_kernel<<<dim3(32, 24), 256, 0, stream>>>(qhb, khb, vtb, seqlen, aob);
    // output projection
    gemm_bt<float><<<dim3(32, 12), 256, 0, stream>>>(aob, wob, bo, out, 4096, 1536, 1536);
}

// Round 3
// 249.408 us; speedup vs baseline: 1.8694x; 1.1445x over previous
//
#include <hip/hip_runtime.h>

typedef __attribute__((ext_vector_type(8))) short bf16x8;
typedef __attribute__((ext_vector_type(8))) unsigned short ushort8;
typedef __attribute__((ext_vector_type(4))) float f32x4;
typedef __attribute__((ext_vector_type(16))) float f32x16;
typedef unsigned short u16;
typedef unsigned int u32;

__device__ inline float bf2f(u16 u) {
    unsigned int x = ((unsigned int)u) << 16;
    float f; __builtin_memcpy(&f, &x, 4); return f;
}
__device__ inline u16 f2bf(float f) {
    unsigned int x; __builtin_memcpy(&x, &f, 4);
    unsigned int r = (x + 0x7FFFu + ((x >> 16) & 1u)) >> 16;
    return (u16)r;
}
__device__ inline u32 cvtpk(float lo, float hi) {
    u32 r;
    asm("v_cvt_pk_bf16_f32 %0, %1, %2" : "=v"(r) : "v"(lo), "v"(hi));
    return r;
}
__device__ inline void store_out(u16* p, float v) { *p = f2bf(v); }
__device__ inline void store_out(float* p, float v) { *p = v; }

// ---------------- prep kernels ----------------
__global__ __launch_bounds__(256) void f32_to_bf16_kernel(const float* __restrict__ src,
                                                          u16* __restrict__ dst, int n8) {
    int i = blockIdx.x * 256 + threadIdx.x;
    if (i >= n8) return;
    float4 a = *(const float4*)(src + (size_t)i * 8);
    float4 b = *(const float4*)(src + (size_t)i * 8 + 4);
    ushort8 o;
    o[0] = f2bf(a.x); o[1] = f2bf(a.y); o[2] = f2bf(a.z); o[3] = f2bf(a.w);
    o[4] = f2bf(b.x); o[5] = f2bf(b.y); o[6] = f2bf(b.z); o[7] = f2bf(b.w);
    *(ushort8*)(dst + (size_t)i * 8) = o;
}

// rope table: [2048][64][2] f32 from freqs [1024][64][2]
__global__ __launch_bounds__(256) void build_rope_kernel(const float* __restrict__ freqs,
                                                         float* __restrict__ rope) {
    int i = blockIdx.x * 256 + threadIdx.x;  // 0..131071
    int s = i >> 6, j = i & 63;
    int fi = s >> 8, hi = (s >> 4) & 15, wi = s & 15;
    int pos = (j < 22) ? fi : ((j < 43) ? hi : wi);
    rope[s * 128 + j * 2]     = freqs[pos * 128 + j * 2];
    rope[s * 128 + j * 2 + 1] = freqs[pos * 128 + j * 2 + 1];
}

// ---------------- GEMM: A[M,K] bf16 row-major, B[N,K] bf16 row-major (B^T gemm), + bias ----------------
template <typename OutT>
__global__ __launch_bounds__(256) void gemm_bt(const u16* __restrict__ A, const u16* __restrict__ Bw,
                                               const float* __restrict__ bias, OutT* __restrict__ C,
                                               int M, int N, int K) {
    __shared__ __align__(16) u16 As[128 * 32];
    __shared__ __align__(16) u16 Bs[128 * 32];
    const int tid = threadIdx.x;
    const int w = tid >> 6, l = tid & 63;
    const int lg = l >> 4, li = l & 15;
    const int row0 = blockIdx.x * 128, col0 = blockIdx.y * 128;
    const int wr = (w >> 1) * 64, wc = (w & 1) * 64;

    f32x4 acc[4][4] = {};

    for (int k0 = 0; k0 < K; k0 += 32) {
#pragma unroll
        for (int c = 0; c < 2; ++c) {
            int idx = c * 256 + tid;           // 0..511 chunks of 8 elems
            int r = idx >> 2, col8 = (idx & 3) * 8;
            const u16* ga = A + (size_t)(row0 + r) * K + k0 + col8;
            const u16* gb = Bw + (size_t)(col0 + r) * K + k0 + col8;
            __builtin_amdgcn_global_load_lds((const __attribute__((address_space(1))) void*)ga,
                (__attribute__((address_space(3))) void*)((char*)As + c * 4096 + w * 1024), 16, 0, 0);
            __builtin_amdgcn_global_load_lds((const __attribute__((address_space(1))) void*)gb,
                (__attribute__((address_space(3))) void*)((char*)Bs + c * 4096 + w * 1024), 16, 0, 0);
        }
        __syncthreads();
        bf16x8 af[4], bfr[4];
#pragma unroll
        for (int m = 0; m < 4; ++m) af[m] = *(const bf16x8*)(As + (wr + m * 16 + li) * 32 + lg * 8);
#pragma unroll
        for (int n = 0; n < 4; ++n) bfr[n] = *(const bf16x8*)(Bs + (wc + n * 16 + li) * 32 + lg * 8);
#pragma unroll
        for (int m = 0; m < 4; ++m)
#pragma unroll
            for (int n = 0; n < 4; ++n)
                acc[m][n] = __builtin_amdgcn_mfma_f32_16x16x32_bf16(af[m], bfr[n], acc[m][n], 0, 0, 0);
        __syncthreads();
    }

#pragma unroll
    for (int m = 0; m < 4; ++m) {
#pragma unroll
        for (int n = 0; n < 4; ++n) {
#pragma unroll
            for (int j = 0; j < 4; ++j) {
                int r = row0 + wr + m * 16 + lg * 4 + j;
                int cc = col0 + wc + n * 16 + li;
                float v = acc[m][n][j] + bias[cc];
                store_out(&C[(size_t)r * N + cc], v);
            }
        }
    }
}

// ---------------- rmsnorm + rope + head-major scatter (q,k only) ----------------
__global__ __launch_bounds__(256) void rmsrope_kernel(const u16* __restrict__ qkv,
                                                      const float* __restrict__ wq_n,
                                                      const float* __restrict__ wk_n,
                                                      const float* __restrict__ rope,
                                                      u16* __restrict__ qh, u16* __restrict__ kh) {
    int row = blockIdx.x;              // 0..4095
    int b = row >> 11, s = row & 2047;
    int t = threadIdx.x;
    const u16* pr = qkv + (size_t)row * 4608;
    int c0 = t * 6;

    float q[6], k[6];
#pragma unroll
    for (int i = 0; i < 3; ++i) {
        ushort2 uq = *(const ushort2*)(pr + c0 + 2 * i);
        ushort2 uk = *(const ushort2*)(pr + 1536 + c0 + 2 * i);
        q[2 * i] = bf2f(uq.x); q[2 * i + 1] = bf2f(uq.y);
        k[2 * i] = bf2f(uk.x); k[2 * i + 1] = bf2f(uk.y);
    }
    float sq = 0.f, sk = 0.f;
#pragma unroll
    for (int i = 0; i < 6; ++i) { sq += q[i] * q[i]; sk += k[i] * k[i]; }
#pragma unroll
    for (int off = 32; off >= 1; off >>= 1) {
        sq += __shfl_down(sq, off);
        sk += __shfl_down(sk, off);
    }
    __shared__ float red[8];
    int w = t >> 6, l = t & 63;
    if (l == 0) { red[w] = sq; red[w + 4] = sk; }
    __syncthreads();
    float rq = rsqrtf((red[0] + red[1] + red[2] + red[3]) * (1.0f / 1536.0f) + 1e-6f);
    float rk = rsqrtf((red[4] + red[5] + red[6] + red[7]) * (1.0f / 1536.0f) + 1e-6f);

#pragma unroll
    for (int i = 0; i < 3; ++i) {
        int c = c0 + 2 * i;
        int h = c >> 7, d = c & 127;
        float cs = rope[s * 128 + d];
        float sn = rope[s * 128 + d + 1];
        float qa = q[2 * i] * rq * wq_n[c], qb = q[2 * i + 1] * rq * wq_n[c + 1];
        float ka = k[2 * i] * rk * wk_n[c], kb = k[2 * i + 1] * rk * wk_n[c + 1];
        size_t o = ((size_t)(b * 12 + h) * 2048 + s) * 128 + d;
        ushort2 qo, ko;
        qo.x = f2bf(qa * cs - qb * sn); qo.y = f2bf(qa * sn + qb * cs);
        ko.x = f2bf(ka * cs - kb * sn); ko.y = f2bf(ka * sn + kb * cs);
        *(ushort2*)(qh + o) = qo;
        *(ushort2*)(kh + o) = ko;
    }
}

// ---------------- V transpose: qkv v-slice [4096][4608] -> vT [24][128][2048] ----------------
// kv dim stored PERMUTED: within each 16-position block, position p holds kv with bits2,3 swapped.
__global__ __launch_bounds__(256) void vtrans_kernel(const u16* __restrict__ qkv,
                                                     u16* __restrict__ vt) {
    const int s0 = blockIdx.x * 64;
    const int d0 = blockIdx.y * 64;
    const int bh = blockIdx.z;
    const int b = bh / 12, h = bh % 12;
    const int t = threadIdx.x;

    __shared__ __align__(16) u16 L[64 * 72];   // rows s (0..63), swizzled d-blocks

#pragma unroll
    for (int j = 0; j < 2; ++j) {
        int idx = j * 256 + t;                  // 0..511
        int s = idx >> 3, c8 = idx & 7;
        ushort8 v8 = *(const ushort8*)(qkv + (size_t)(b * 2048 + s0 + s) * 4608 + 3072 + h * 128 + d0 + c8 * 8);
        int pb = c8 ^ ((s >> 3) & 7);
        *(ushort8*)(L + s * 72 + pb * 8) = v8;
    }
    __syncthreads();
#pragma unroll
    for (int j = 0; j < 2; ++j) {
        int idx = j * 256 + t;
        int d = idx >> 3, s8 = idx & 7;
        ushort8 o;
#pragma unroll
        for (int i = 0; i < 8; ++i) {
            int ps = s8 * 8 + i;                                  // output position 0..63
            int v4 = ps & 15;
            int ls = (ps & ~15) | (v4 & 3) | ((v4 & 4) << 1) | ((v4 & 8) >> 1);  // swap bits 2,3
            o[i] = L[ls * 72 + ((((d >> 3) ^ (ls >> 3)) & 7) << 3) + (d & 7)];
        }
        *(ushort8*)(vt + (size_t)bh * 128 * 2048 + (size_t)(d0 + d) * 2048 + s0 + s8 * 8) = o;
    }
}

// ---------------- flash attention (swapped-operand 32x32, 2 waves x 32 q rows) ----------------
// qh/kh: [BH=24][2048][128] bf16; vt: [24][128][2048] bf16 (V^T, kv-permuted). out: [4096][1536] bf16
__global__ __launch_bounds__(128, 2) void attn_kernel(const u16* __restrict__ qh, const u16* __restrict__ kh,
                                                      const u16* __restrict__ vt, const int* __restrict__ seq_lens,
                                                      u16* __restrict__ aout) {
    const int qt = blockIdx.x;        // 32 q tiles of 64
    const int bh = blockIdx.y;        // 24
    const int b = bh / 12, h = bh % 12;
    const int tid = threadIdx.x;      // 0..127
    const int w = tid >> 6, l = tid & 63;
    const int q5 = l & 31;            // q col within wave tile / also d,kv row index
    const int hi = l >> 5;
    const int seqlen = seq_lens[b];

    __shared__ __align__(16) char smem[32768];
    u16* Ks = (u16*)smem;             // [64][128], 16B-block swizzled by (row&15)
    u16* Vs = (u16*)(smem + 16384);   // [128][64], 16B-block swizzled by (row&7)

    const size_t hbase = (size_t)bh * 2048 * 128;
    const u16* kb = kh + hbase;
    const u16* vtb = vt + hbase;

    // Q B-fragments: row q, d = kd*16 + hi*8 + i
    const int qrow = qt * 64 + w * 32 + q5;
    bf16x8 qf[8];
    {
        const u16* qp = qh + hbase + (size_t)qrow * 128 + hi * 8;
#pragma unroll
        for (int kd = 0; kd < 8; ++kd) qf[kd] = *(const bf16x8*)(qp + kd * 16);
    }

    f32x16 oacc[4] = {};              // O^T tiles: d = dt*32 + (r&3)+8*(r>>2)+4*hi, q col = q5
    float m_run = -3e38f, l_run = 0.f;
    const float c2 = 0.08838834764831845f * 1.44269504088896341f;  // 1/sqrt(128) * log2(e)

    for (int kv0 = 0; kv0 < 2048; kv0 += 64) {
        __syncthreads();
#pragma unroll
        for (int i = 0; i < 8; ++i) {
            int p = i * 128 + tid;
            int kr = p >> 4, kc = p & 15;
            __builtin_amdgcn_global_load_lds(
                (const __attribute__((address_space(1))) void*)(kb + (size_t)(kv0 + kr) * 128 + ((kc ^ (kr & 15)) << 3)),
                (__attribute__((address_space(3))) void*)((char*)Ks + (i * 128 + w * 64) * 16), 16, 0, 0);
            int vr = p >> 3, vc = p & 7;
            __builtin_amdgcn_global_load_lds(
                (const __attribute__((address_space(1))) void*)(vtb + (size_t)vr * 2048 + kv0 + ((vc ^ (vr & 7)) << 3)),
                (__attribute__((address_space(3))) void*)((char*)Vs + (i * 128 + w * 64) * 16), 16, 0, 0);
        }
        __syncthreads();

        // S^T = mfma(K, Q): col = q5 (q), rows = kv pattern
        f32x16 sacc[2] = {};
#pragma unroll
        for (int t = 0; t < 2; ++t) {
            int row = t * 32 + q5;
#pragma unroll
            for (int kd = 0; kd < 8; ++kd) {
                int bk = (2 * kd + hi) ^ (q5 & 15);
                bf16x8 kf = *(const bf16x8*)(Ks + row * 128 + bk * 8);
                sacc[t] = __builtin_amdgcn_mfma_f32_32x32x16_bf16(kf, qf[kd], sacc[t], 0, 0, 0);
            }
        }

        // mask (kv = kv0 + 32t + 8m + 4hi + r)
        if (kv0 + 64 > seqlen) {
#pragma unroll
            for (int t = 0; t < 2; ++t)
#pragma unroll
                for (int m = 0; m < 4; ++m)
#pragma unroll
                    for (int r = 0; r < 4; ++r) {
                        int kv = kv0 + t * 32 + m * 8 + hi * 4 + r;
                        if (kv >= seqlen) sacc[t][m * 4 + r] = -1e30f;
                    }
        }

        // online softmax (raw-score domain; scale folded into exp2)
        float pmax = sacc[0][0];
#pragma unroll
        for (int t = 0; t < 2; ++t)
#pragma unroll
            for (int r = 0; r < 16; ++r) pmax = fmaxf(pmax, sacc[t][r]);
        pmax = fmaxf(pmax, __shfl_xor(pmax, 32));

        int defer = __all(pmax <= m_run + 62.7f);
        if (!defer) {
            float mnew = fmaxf(m_run, pmax);
            float alpha = __builtin_amdgcn_exp2f((m_run - mnew) * c2);
#pragma unroll
            for (int dt = 0; dt < 4; ++dt)
#pragma unroll
                for (int r = 0; r < 16; ++r) oacc[dt][r] *= alpha;
            l_run *= alpha;
            m_run = mnew;
        }

        float ls = 0.f;
        u32 Wp[2][4][2];
#pragma unroll
        for (int t = 0; t < 2; ++t)
#pragma unroll
            for (int m = 0; m < 4; ++m) {
                float p0 = __builtin_amdgcn_exp2f((sacc[t][4 * m + 0] - m_run) * c2);
                float p1 = __builtin_amdgcn_exp2f((sacc[t][4 * m + 1] - m_run) * c2);
                float p2 = __builtin_amdgcn_exp2f((sacc[t][4 * m + 2] - m_run) * c2);
                float p3 = __builtin_amdgcn_exp2f((sacc[t][4 * m + 3] - m_run) * c2);
                ls += (p0 + p1) + (p2 + p3);
                Wp[t][m][0] = cvtpk(p0, p1);
                Wp[t][m][1] = cvtpk(p2, p3);
            }
        ls += __shfl_xor(ls, 32);
        l_run += ls;

        // O^T += mfma(V^T, P): in-lane P fragments, kv map = bits2,3-swapped (matches vt permutation)
#pragma unroll
        for (int t = 0; t < 2; ++t)
#pragma unroll
            for (int c = 0; c < 2; ++c) {
                union { u32 u[4]; bf16x8 v; } pu;
                pu.u[0] = Wp[t][2 * c][0]; pu.u[1] = Wp[t][2 * c][1];
                pu.u[2] = Wp[t][2 * c + 1][0]; pu.u[3] = Wp[t][2 * c + 1][1];
                int bk = 4 * t + 2 * c + hi;
#pragma unroll
                for (int dt = 0; dt < 4; ++dt) {
                    int drow = dt * 32 + q5;
                    int pb = bk ^ (drow & 7);
                    bf16x8 vf = *(const bf16x8*)(Vs + drow * 64 + pb * 8);
                    oacc[dt] = __builtin_amdgcn_mfma_f32_32x32x16_bf16(vf, pu.v, oacc[dt], 0, 0, 0);
                }
            }
    }

    // epilogue: transpose O^T -> O via LDS, normalize, coalesced store
    __syncthreads();
    u32* Lq = (u32*)smem + w * 2144;   // [32][67] u32 per wave
    float inv_l = 1.0f / l_run;
#pragma unroll
    for (int dt = 0; dt < 4; ++dt)
#pragma unroll
        for (int m = 0; m < 4; ++m) {
            u32 w0 = cvtpk(oacc[dt][4 * m + 0] * inv_l, oacc[dt][4 * m + 1] * inv_l);
            u32 w1 = cvtpk(oacc[dt][4 * m + 2] * inv_l, oacc[dt][4 * m + 3] * inv_l);
            int widx = dt * 16 + 4 * m + 2 * hi;
            Lq[q5 * 67 + widx] = w0;
            Lq[q5 * 67 + widx + 1] = w1;
        }
    __builtin_amdgcn_s_waitcnt(0);   // lgkm drain for own-wave LDS writes
#pragma unroll
    for (int pp = 0; pp < 8; ++pp) {
        int qq = pp * 4 + (l >> 4);
        int cc = l & 15;
        union { u32 u[4]; ushort8 v; } ou;
        ou.u[0] = Lq[qq * 67 + cc * 4 + 0];
        ou.u[1] = Lq[qq * 67 + cc * 4 + 1];
        ou.u[2] = Lq[qq * 67 + cc * 4 + 2];
        ou.u[3] = Lq[qq * 67 + cc * 4 + 3];
        size_t off = ((size_t)(b * 2048 + qt * 64 + w * 32 + qq)) * 1536 + h * 128 + cc * 8;
        *(ushort8*)(aout + off) = ou.v;
    }
}

// ---------------- host ----------------
extern "C" void kernel_launch(void* const* d_in, const int* in_sizes, int n_in,
                              void* d_out, int out_size, void* d_ws, size_t ws_size,
                              hipStream_t stream) {
    const float* x    = (const float*)d_in[0];
    const int* seqlen = (const int*)d_in[1];
    const float* freqs = (const float*)d_in[3];
    const float* Wq = (const float*)d_in[4];  const float* bq = (const float*)d_in[5];
    const float* Wk = (const float*)d_in[6];  const float* bk = (const float*)d_in[7];
    const float* Wv = (const float*)d_in[8];  const float* bv = (const float*)d_in[9];
    const float* Wo = (const float*)d_in[10]; const float* bo = (const float*)d_in[11];
    const float* wqn = (const float*)d_in[12];
    const float* wkn = (const float*)d_in[13];
    float* out = (float*)d_out;

    char* ws = (char*)d_ws;
    u16*   xb   = (u16*)(ws);                    // 12,582,912
    u16*   wqkv = (u16*)(ws + 12582912);         // 14,155,776
    u16*   wob  = (u16*)(ws + 26738688);         //  4,718,592
    float* bqkv = (float*)(ws + 31457280);       //     18,432
    float* rope = (float*)(ws + 31475712);       //  1,048,576
    u16*   qkv  = (u16*)(ws + 32524288);         // 37,748,736
    u16*   qhb  = (u16*)(ws + 70273024);         // 12,582,912
    u16*   khb  = (u16*)(ws + 82855936);         // 12,582,912
    u16*   vtb  = (u16*)(ws + 95438848);         // 12,582,912 (V^T [24][128][2048], kv-permuted)
    u16*   aob  = (u16*)(ws + 108021760);        // 12,582,912  (end 120,604,672)

    f32_to_bf16_kernel<<<3072, 256, 0, stream>>>(x, xb, 786432);
    f32_to_bf16_kernel<<<1152, 256, 0, stream>>>(Wq, wqkv, 294912);
    f32_to_bf16_kernel<<<1152, 256, 0, stream>>>(Wk, wqkv + 2359296, 294912);
    f32_to_bf16_kernel<<<1152, 256, 0, stream>>>(Wv, wqkv + 4718592, 294912);
    f32_to_bf16_kernel<<<1152, 256, 0, stream>>>(Wo, wob, 294912);
    hipMemcpyAsync(bqkv,        bq, 1536 * 4, hipMemcpyDeviceToDevice, stream);
    hipMemcpyAsync(bqkv + 1536, bk, 1536 * 4, hipMemcpyDeviceToDevice, stream);
    hipMemcpyAsync(bqkv + 3072, bv, 1536 * 4, hipMemcpyDeviceToDevice, stream);
    build_rope_kernel<<<512, 256, 0, stream>>>(freqs, rope);

    gemm_bt<u16><<<dim3(32, 36), 256, 0, stream>>>(xb, wqkv, bqkv, qkv, 4096, 4608, 1536);
    rmsrope_kernel<<<4096, 256, 0, stream>>>(qkv, wqn, wkn, rope, qhb, khb);
    vtrans_kernel<<<dim3(32, 2, 24), 256, 0, stream>>>(qkv, vtb);
    attn_kernel<<<dim3(32, 24), 128, 0, stream>>>(qhb, khb, vtb, seqlen, aob);
    gemm_bt<float><<<dim3(32, 12), 256, 0, stream>>>(aob, wob, bo, out, 4096, 1536, 1536);
}

// Round 4
// 228.514 us; speedup vs baseline: 2.0403x; 1.0914x over previous
//
#include <hip/hip_runtime.h>

typedef __attribute__((ext_vector_type(8))) short bf16x8;
typedef __attribute__((ext_vector_type(8))) unsigned short ushort8;
typedef __attribute__((ext_vector_type(4))) float f32x4;
typedef __attribute__((ext_vector_type(16))) float f32x16;
typedef unsigned short u16;
typedef unsigned int u32;

__device__ inline float bf2f(u16 u) {
    unsigned int x = ((unsigned int)u) << 16;
    float f; __builtin_memcpy(&f, &x, 4); return f;
}
__device__ inline u16 f2bf(float f) {
    unsigned int x; __builtin_memcpy(&x, &f, 4);
    unsigned int r = (x + 0x7FFFu + ((x >> 16) & 1u)) >> 16;
    return (u16)r;
}
__device__ inline u32 cvtpk(float lo, float hi) {
    u32 r;
    asm("v_cvt_pk_bf16_f32 %0, %1, %2" : "=v"(r) : "v"(lo), "v"(hi));
    return r;
}
__device__ inline void store_out(u16* p, float v) { *p = f2bf(v); }
__device__ inline void store_out(float* p, float v) { *p = v; }

// ---------------- prep kernels ----------------
__global__ __launch_bounds__(256) void f32_to_bf16_kernel(const float* __restrict__ src,
                                                          u16* __restrict__ dst, int n8) {
    int i = blockIdx.x * 256 + threadIdx.x;
    if (i >= n8) return;
    float4 a = *(const float4*)(src + (size_t)i * 8);
    float4 b = *(const float4*)(src + (size_t)i * 8 + 4);
    ushort8 o;
    o[0] = f2bf(a.x); o[1] = f2bf(a.y); o[2] = f2bf(a.z); o[3] = f2bf(a.w);
    o[4] = f2bf(b.x); o[5] = f2bf(b.y); o[6] = f2bf(b.z); o[7] = f2bf(b.w);
    *(ushort8*)(dst + (size_t)i * 8) = o;
}

// all four 1536x1536 weight converts in one launch: segs q,k,v -> wqkv, o -> wob
__global__ __launch_bounds__(256) void wconv_kernel(const float* __restrict__ Wq, const float* __restrict__ Wk,
                                                    const float* __restrict__ Wv, const float* __restrict__ Wo,
                                                    u16* __restrict__ wqkv, u16* __restrict__ wob) {
    int i = blockIdx.x * 256 + threadIdx.x;      // 0..1179647
    int seg = i / 294912, j = i - seg * 294912;
    const float* src = (seg == 0) ? Wq : (seg == 1) ? Wk : (seg == 2) ? Wv : Wo;
    u16* dst = (seg < 3) ? (wqkv + (size_t)seg * 2359296) : wob;
    float4 a = *(const float4*)(src + (size_t)j * 8);
    float4 b = *(const float4*)(src + (size_t)j * 8 + 4);
    ushort8 o;
    o[0] = f2bf(a.x); o[1] = f2bf(a.y); o[2] = f2bf(a.z); o[3] = f2bf(a.w);
    o[4] = f2bf(b.x); o[5] = f2bf(b.y); o[6] = f2bf(b.z); o[7] = f2bf(b.w);
    *(ushort8*)(dst + (size_t)j * 8) = o;
}

// rope table: [2048][64][2] f32 from freqs [1024][64][2]
__global__ __launch_bounds__(256) void build_rope_kernel(const float* __restrict__ freqs,
                                                         float* __restrict__ rope) {
    int i = blockIdx.x * 256 + threadIdx.x;  // 0..131071
    int s = i >> 6, j = i & 63;
    int fi = s >> 8, hi = (s >> 4) & 15, wi = s & 15;
    int pos = (j < 22) ? fi : ((j < 43) ? hi : wi);
    rope[s * 128 + j * 2]     = freqs[pos * 128 + j * 2];
    rope[s * 128 + j * 2 + 1] = freqs[pos * 128 + j * 2 + 1];
}

// ---------------- GEMM: A[M,K] bf16 rm, B[N,K] bf16 rm (B^T gemm), + bias ----------------
// triple-buffered LDS, depth-2 prefetch with counted vmcnt (requires (K/32)%3==0, K>=64)
template <typename OutT>
__global__ __launch_bounds__(256) void gemm_bt(const u16* __restrict__ A, const u16* __restrict__ Bw,
                                               const float* __restrict__ bias, OutT* __restrict__ C,
                                               int M, int N, int K) {
    __shared__ __align__(16) u16 As[3][4096];
    __shared__ __align__(16) u16 Bs[3][4096];
    const int tid = threadIdx.x;
    const int w = tid >> 6, l = tid & 63;
    const int lg = l >> 4, li = l & 15;
    const int row0 = blockIdx.x * 128, col0 = blockIdx.y * 128;
    const int wr = (w >> 1) * 64, wc = (w & 1) * 64;
    const int nt = K >> 5;

    f32x4 acc[4][4] = {};

    auto STAGE = [&](int bi, int t) {
        int k0 = t << 5;
#pragma unroll
        for (int c = 0; c < 2; ++c) {
            int idx = c * 256 + tid;
            int r = idx >> 2, col8 = (idx & 3) * 8;
            __builtin_amdgcn_global_load_lds(
                (const __attribute__((address_space(1))) void*)(A + (size_t)(row0 + r) * K + k0 + col8),
                (__attribute__((address_space(3))) void*)((char*)&As[0][0] + bi * 8192 + c * 4096 + w * 1024), 16, 0, 0);
            __builtin_amdgcn_global_load_lds(
                (const __attribute__((address_space(1))) void*)(Bw + (size_t)(col0 + r) * K + k0 + col8),
                (__attribute__((address_space(3))) void*)((char*)&Bs[0][0] + bi * 8192 + c * 4096 + w * 1024), 16, 0, 0);
        }
    };

    STAGE(0, 0);
    STAGE(1, 1);
    for (int tb = 0; tb < nt; tb += 3) {
#pragma unroll
        for (int j = 0; j < 3; ++j) {
            const int t = tb + j;
            if (t + 2 < nt) {
                STAGE((j + 2) % 3, t + 2);
                asm volatile("s_waitcnt vmcnt(8)" ::: "memory");
            } else if (t + 1 < nt) {
                asm volatile("s_waitcnt vmcnt(4)" ::: "memory");
            } else {
                asm volatile("s_waitcnt vmcnt(0)" ::: "memory");
            }
            __builtin_amdgcn_s_barrier();
            __builtin_amdgcn_sched_barrier(0);
            const u16* as = &As[j][0];
            const u16* bs = &Bs[j][0];
            bf16x8 af[4], bfr[4];
#pragma unroll
            for (int m = 0; m < 4; ++m) af[m] = *(const bf16x8*)(as + (wr + m * 16 + li) * 32 + lg * 8);
#pragma unroll
            for (int n = 0; n < 4; ++n) bfr[n] = *(const bf16x8*)(bs + (wc + n * 16 + li) * 32 + lg * 8);
#pragma unroll
            for (int m = 0; m < 4; ++m)
#pragma unroll
                for (int n = 0; n < 4; ++n)
                    acc[m][n] = __builtin_amdgcn_mfma_f32_16x16x32_bf16(af[m], bfr[n], acc[m][n], 0, 0, 0);
            __builtin_amdgcn_sched_barrier(0);
            __builtin_amdgcn_s_barrier();
        }
    }

#pragma unroll
    for (int m = 0; m < 4; ++m) {
#pragma unroll
        for (int n = 0; n < 4; ++n) {
#pragma unroll
            for (int j = 0; j < 4; ++j) {
                int r = row0 + wr + m * 16 + lg * 4 + j;
                int cc = col0 + wc + n * 16 + li;
                float v = acc[m][n][j] + bias[cc];
                store_out(&C[(size_t)r * N + cc], v);
            }
        }
    }
}

// ---------------- rmsnorm + rope + head-major scatter (q,k only) ----------------
__global__ __launch_bounds__(256) void rmsrope_kernel(const u16* __restrict__ qkv,
                                                      const float* __restrict__ wq_n,
                                                      const float* __restrict__ wk_n,
                                                      const float* __restrict__ rope,
                                                      u16* __restrict__ qh, u16* __restrict__ kh) {
    int row = blockIdx.x;              // 0..4095
    int b = row >> 11, s = row & 2047;
    int t = threadIdx.x;
    const u16* pr = qkv + (size_t)row * 4608;
    int c0 = t * 6;

    float q[6], k[6];
#pragma unroll
    for (int i = 0; i < 3; ++i) {
        ushort2 uq = *(const ushort2*)(pr + c0 + 2 * i);
        ushort2 uk = *(const ushort2*)(pr + 1536 + c0 + 2 * i);
        q[2 * i] = bf2f(uq.x); q[2 * i + 1] = bf2f(uq.y);
        k[2 * i] = bf2f(uk.x); k[2 * i + 1] = bf2f(uk.y);
    }
    float sq = 0.f, sk = 0.f;
#pragma unroll
    for (int i = 0; i < 6; ++i) { sq += q[i] * q[i]; sk += k[i] * k[i]; }
#pragma unroll
    for (int off = 32; off >= 1; off >>= 1) {
        sq += __shfl_down(sq, off);
        sk += __shfl_down(sk, off);
    }
    __shared__ float red[8];
    int w = t >> 6, l = t & 63;
    if (l == 0) { red[w] = sq; red[w + 4] = sk; }
    __syncthreads();
    float rq = rsqrtf((red[0] + red[1] + red[2] + red[3]) * (1.0f / 1536.0f) + 1e-6f);
    float rk = rsqrtf((red[4] + red[5] + red[6] + red[7]) * (1.0f / 1536.0f) + 1e-6f);

#pragma unroll
    for (int i = 0; i < 3; ++i) {
        int c = c0 + 2 * i;
        int h = c >> 7, d = c & 127;
        float cs = rope[s * 128 + d];
        float sn = rope[s * 128 + d + 1];
        float qa = q[2 * i] * rq * wq_n[c], qb = q[2 * i + 1] * rq * wq_n[c + 1];
        float ka = k[2 * i] * rk * wk_n[c], kb = k[2 * i + 1] * rk * wk_n[c + 1];
        size_t o = ((size_t)(b * 12 + h) * 2048 + s) * 128 + d;
        ushort2 qo, ko;
        qo.x = f2bf(qa * cs - qb * sn); qo.y = f2bf(qa * sn + qb * cs);
        ko.x = f2bf(ka * cs - kb * sn); ko.y = f2bf(ka * sn + kb * cs);
        *(ushort2*)(qh + o) = qo;
        *(ushort2*)(kh + o) = ko;
    }
}

// ---------------- V transpose: qkv v-slice [4096][4608] -> vT [24][128][2048] ----------------
// kv dim stored PERMUTED: within each 16-position block, position p holds kv with bits2,3 swapped.
__global__ __launch_bounds__(256) void vtrans_kernel(const u16* __restrict__ qkv,
                                                     u16* __restrict__ vt) {
    const int s0 = blockIdx.x * 64;
    const int d0 = blockIdx.y * 64;
    const int bh = blockIdx.z;
    const int b = bh / 12, h = bh % 12;
    const int t = threadIdx.x;

    __shared__ __align__(16) u16 L[64 * 72];   // rows s (0..63), swizzled d-blocks

#pragma unroll
    for (int j = 0; j < 2; ++j) {
        int idx = j * 256 + t;                  // 0..511
        int s = idx >> 3, c8 = idx & 7;
        ushort8 v8 = *(const ushort8*)(qkv + (size_t)(b * 2048 + s0 + s) * 4608 + 3072 + h * 128 + d0 + c8 * 8);
        int pb = c8 ^ ((s >> 3) & 7);
        *(ushort8*)(L + s * 72 + pb * 8) = v8;
    }
    __syncthreads();
#pragma unroll
    for (int j = 0; j < 2; ++j) {
        int idx = j * 256 + t;
        int d = idx >> 3, s8 = idx & 7;
        ushort8 o;
#pragma unroll
        for (int i = 0; i < 8; ++i) {
            int ps = s8 * 8 + i;                                  // output position 0..63
            int v4 = ps & 15;
            int ls = (ps & ~15) | (v4 & 3) | ((v4 & 4) << 1) | ((v4 & 8) >> 1);  // swap bits 2,3
            o[i] = L[ls * 72 + ((((d >> 3) ^ (ls >> 3)) & 7) << 3) + (d & 7)];
        }
        *(ushort8*)(vt + (size_t)bh * 128 * 2048 + (size_t)(d0 + d) * 2048 + s0 + s8 * 8) = o;
    }
}

// ---------------- flash attention (swapped-operand 32x32, 4 waves x 32 q rows, dbuf prefetch) ----------------
// qh/kh: [BH=24][2048][128] bf16; vt: [24][128][2048] bf16 (V^T, kv-permuted). out: [4096][1536] bf16
__global__ __launch_bounds__(256, 2) void attn_kernel(const u16* __restrict__ qh, const u16* __restrict__ kh,
                                                      const u16* __restrict__ vt, const int* __restrict__ seq_lens,
                                                      u16* __restrict__ aout) {
    const int qt = blockIdx.x;        // 16 q tiles of 128
    const int bh = blockIdx.y;        // 24
    const int b = bh / 12, h = bh % 12;
    const int tid = threadIdx.x;      // 0..255
    const int w = tid >> 6, l = tid & 63;
    const int q5 = l & 31;
    const int hi = l >> 5;
    const int seqlen = seq_lens[b];

    __shared__ __align__(16) char smem[65536];  // Ks[2][64*128] | Vs[2][128*64]

    const size_t hbase = (size_t)bh * 2048 * 128;
    const u16* kb = kh + hbase;
    const u16* vtb = vt + hbase;

    const int qrow = qt * 128 + w * 32 + q5;
    bf16x8 qf[8];
    {
        const u16* qp = qh + hbase + (size_t)qrow * 128 + hi * 8;
#pragma unroll
        for (int kd = 0; kd < 8; ++kd) qf[kd] = *(const bf16x8*)(qp + kd * 16);
    }

    auto STAGE = [&](int bi, int kv0) {
#pragma unroll
        for (int i = 0; i < 4; ++i) {
            int p = i * 256 + tid;
            int kr = p >> 4, kc = p & 15;
            __builtin_amdgcn_global_load_lds(
                (const __attribute__((address_space(1))) void*)(kb + (size_t)(kv0 + kr) * 128 + ((kc ^ (kr & 15)) << 3)),
                (__attribute__((address_space(3))) void*)(smem + bi * 16384 + i * 4096 + w * 1024), 16, 0, 0);
            int vr = p >> 3, vc = p & 7;
            __builtin_amdgcn_global_load_lds(
                (const __attribute__((address_space(1))) void*)(vtb + (size_t)vr * 2048 + kv0 + ((vc ^ (vr & 7)) << 3)),
                (__attribute__((address_space(3))) void*)(smem + 32768 + bi * 16384 + i * 4096 + w * 1024), 16, 0, 0);
        }
    };

    f32x16 oacc[4] = {};              // O^T tiles: d = dt*32 + (r&3)+8*(r>>2)+4*hi, q col = q5
    float m_run = -3e38f, l_run = 0.f;
    const float c2 = 0.08838834764831845f * 1.44269504088896341f;  // 1/sqrt(128) * log2(e)

    STAGE(0, 0);
    for (int t = 0; t < 32; ++t) {
        const int cur = t & 1;
        const int kv0 = t * 64;
        if (t < 31) {
            STAGE(cur ^ 1, kv0 + 64);
            asm volatile("s_waitcnt vmcnt(8)" ::: "memory");
        } else {
            asm volatile("s_waitcnt vmcnt(0)" ::: "memory");
        }
        __builtin_amdgcn_s_barrier();
        __builtin_amdgcn_sched_barrier(0);

        const u16* Ks = (const u16*)(smem + cur * 16384);
        const u16* Vs = (const u16*)(smem + 32768 + cur * 16384);

        // S^T = mfma(K, Q): col = q5 (q), rows = kv pattern
        f32x16 sacc[2] = {};
        __builtin_amdgcn_s_setprio(1);
#pragma unroll
        for (int tt = 0; tt < 2; ++tt) {
            int row = tt * 32 + q5;
#pragma unroll
            for (int kd = 0; kd < 8; ++kd) {
                int bk = (2 * kd + hi) ^ (q5 & 15);
                bf16x8 kf = *(const bf16x8*)(Ks + row * 128 + bk * 8);
                sacc[tt] = __builtin_amdgcn_mfma_f32_32x32x16_bf16(kf, qf[kd], sacc[tt], 0, 0, 0);
            }
        }
        __builtin_amdgcn_s_setprio(0);

        // mask (kv = kv0 + 32tt + 8m + 4hi + r)
        if (kv0 + 64 > seqlen) {
#pragma unroll
            for (int tt = 0; tt < 2; ++tt)
#pragma unroll
                for (int m = 0; m < 4; ++m)
#pragma unroll
                    for (int r = 0; r < 4; ++r) {
                        int kv = kv0 + tt * 32 + m * 8 + hi * 4 + r;
                        if (kv >= seqlen) sacc[tt][m * 4 + r] = -1e30f;
                    }
        }

        // online softmax (raw-score domain; scale folded into exp2)
        float pmax = sacc[0][0];
#pragma unroll
        for (int tt = 0; tt < 2; ++tt)
#pragma unroll
            for (int r = 0; r < 16; ++r) pmax = fmaxf(pmax, sacc[tt][r]);
        pmax = fmaxf(pmax, __shfl_xor(pmax, 32));

        int defer = __all(pmax <= m_run + 62.7f);
        if (!defer) {
            float mnew = fmaxf(m_run, pmax);
            float alpha = __builtin_amdgcn_exp2f((m_run - mnew) * c2);
#pragma unroll
            for (int dt = 0; dt < 4; ++dt)
#pragma unroll
                for (int r = 0; r < 16; ++r) oacc[dt][r] *= alpha;
            l_run *= alpha;
            m_run = mnew;
        }

        float ls = 0.f;
        u32 Wp[2][4][2];
#pragma unroll
        for (int tt = 0; tt < 2; ++tt)
#pragma unroll
            for (int m = 0; m < 4; ++m) {
                float p0 = __builtin_amdgcn_exp2f((sacc[tt][4 * m + 0] - m_run) * c2);
                float p1 = __builtin_amdgcn_exp2f((sacc[tt][4 * m + 1] - m_run) * c2);
                float p2 = __builtin_amdgcn_exp2f((sacc[tt][4 * m + 2] - m_run) * c2);
                float p3 = __builtin_amdgcn_exp2f((sacc[tt][4 * m + 3] - m_run) * c2);
                ls += (p0 + p1) + (p2 + p3);
                Wp[tt][m][0] = cvtpk(p0, p1);
                Wp[tt][m][1] = cvtpk(p2, p3);
            }
        ls += __shfl_xor(ls, 32);
        l_run += ls;

        // O^T += mfma(V^T, P): in-lane P fragments, kv map = bits2,3-swapped (matches vt permutation)
        __builtin_amdgcn_s_setprio(1);
#pragma unroll
        for (int tt = 0; tt < 2; ++tt)
#pragma unroll
            for (int c = 0; c < 2; ++c) {
                union { u32 u[4]; bf16x8 v; } pu;
                pu.u[0] = Wp[tt][2 * c][0]; pu.u[1] = Wp[tt][2 * c][1];
                pu.u[2] = Wp[tt][2 * c + 1][0]; pu.u[3] = Wp[tt][2 * c + 1][1];
                int bk = 4 * tt + 2 * c + hi;
#pragma unroll
                for (int dt = 0; dt < 4; ++dt) {
                    int drow = dt * 32 + q5;
                    int pb = bk ^ (drow & 7);
                    bf16x8 vf = *(const bf16x8*)(Vs + drow * 64 + pb * 8);
                    oacc[dt] = __builtin_amdgcn_mfma_f32_32x32x16_bf16(vf, pu.v, oacc[dt], 0, 0, 0);
                }
            }
        __builtin_amdgcn_s_setprio(0);
        __builtin_amdgcn_sched_barrier(0);
        __builtin_amdgcn_s_barrier();
    }

    // epilogue: transpose O^T -> O via LDS, normalize, coalesced store
    __syncthreads();
    u32* Lq = (u32*)smem + w * 2144;   // [32][67] u32 per wave
    float inv_l = 1.0f / l_run;
#pragma unroll
    for (int dt = 0; dt < 4; ++dt)
#pragma unroll
        for (int m = 0; m < 4; ++m) {
            u32 w0 = cvtpk(oacc[dt][4 * m + 0] * inv_l, oacc[dt][4 * m + 1] * inv_l);
            u32 w1 = cvtpk(oacc[dt][4 * m + 2] * inv_l, oacc[dt][4 * m + 3] * inv_l);
            int widx = dt * 16 + 4 * m + 2 * hi;
            Lq[q5 * 67 + widx] = w0;
            Lq[q5 * 67 + widx + 1] = w1;
        }
    __builtin_amdgcn_s_waitcnt(0);   // lgkm drain for own-wave LDS writes
#pragma unroll
    for (int pp = 0; pp < 8; ++pp) {
        int qq = pp * 4 + (l >> 4);
        int cc = l & 15;
        union { u32 u[4]; ushort8 v; } ou;
        ou.u[0] = Lq[qq * 67 + cc * 4 + 0];
        ou.u[1] = Lq[qq * 67 + cc * 4 + 1];
        ou.u[2] = Lq[qq * 67 + cc * 4 + 2];
        ou.u[3] = Lq[qq * 67 + cc * 4 + 3];
        size_t off = ((size_t)(b * 2048 + qt * 128 + w * 32 + qq)) * 1536 + h * 128 + cc * 8;
        *(ushort8*)(aout + off) = ou.v;
    }
}

// ---------------- host ----------------
extern "C" void kernel_launch(void* const* d_in, const int* in_sizes, int n_in,
                              void* d_out, int out_size, void* d_ws, size_t ws_size,
                              hipStream_t stream) {
    const float* x    = (const float*)d_in[0];
    const int* seqlen = (const int*)d_in[1];
    const float* freqs = (const float*)d_in[3];
    const float* Wq = (const float*)d_in[4];  const float* bq = (const float*)d_in[5];
    const float* Wk = (const float*)d_in[6];  const float* bk = (const float*)d_in[7];
    const float* Wv = (const float*)d_in[8];  const float* bv = (const float*)d_in[9];
    const float* Wo = (const float*)d_in[10]; const float* bo = (const float*)d_in[11];
    const float* wqn = (const float*)d_in[12];
    const float* wkn = (const float*)d_in[13];
    float* out = (float*)d_out;

    char* ws = (char*)d_ws;
    u16*   xb   = (u16*)(ws);                    // 12,582,912
    u16*   wqkv = (u16*)(ws + 12582912);         // 14,155,776
    u16*   wob  = (u16*)(ws + 26738688);         //  4,718,592
    float* bqkv = (float*)(ws + 31457280);       //     18,432
    float* rope = (float*)(ws + 31475712);       //  1,048,576
    u16*   qkv  = (u16*)(ws + 32524288);         // 37,748,736
    u16*   qhb  = (u16*)(ws + 70273024);         // 12,582,912
    u16*   khb  = (u16*)(ws + 82855936);         // 12,582,912
    u16*   vtb  = (u16*)(ws + 95438848);         // 12,582,912 (V^T [24][128][2048], kv-permuted)
    u16*   aob  = (u16*)(ws + 108021760);        // 12,582,912  (end 120,604,672)

    f32_to_bf16_kernel<<<3072, 256, 0, stream>>>(x, xb, 786432);
    wconv_kernel<<<4608, 256, 0, stream>>>(Wq, Wk, Wv, Wo, wqkv, wob);
    hipMemcpyAsync(bqkv,        bq, 1536 * 4, hipMemcpyDeviceToDevice, stream);
    hipMemcpyAsync(bqkv + 1536, bk, 1536 * 4, hipMemcpyDeviceToDevice, stream);
    hipMemcpyAsync(bqkv + 3072, bv, 1536 * 4, hipMemcpyDeviceToDevice, stream);
    build_rope_kernel<<<512, 256, 0, stream>>>(freqs, rope);

    gemm_bt<u16><<<dim3(32, 36), 256, 0, stream>>>(xb, wqkv, bqkv, qkv, 4096, 4608, 1536);
    rmsrope_kernel<<<4096, 256, 0, stream>>>(qkv, wqn, wkn, rope, qhb, khb);
    vtrans_kernel<<<dim3(32, 2, 24), 256, 0, stream>>>(qkv, vtb);
    attn_kernel<<<dim3(16, 24), 256, 0, stream>>>(qhb, khb, vtb, seqlen, aob);
    gemm_bt<float><<<dim3(32, 12), 256, 0, stream>>>(aob, wob, bo, out, 4096, 1536, 1536);
}